// Round 18
// baseline (3857.419 us; speedup 1.0000x reference)
//
#include <hip/hip_runtime.h>
#include <stdint.h>

// ---- problem constants ----
constexpr int HD   = 512;
constexpr int TS   = 256;
constexpr int NB   = 64;
constexpr int MBR  = 128;
constexpr int SLAB = MBR * HD;   // 65536 elements per h-slab
constexpr int NG   = 8;          // row groups (16 rows each)
constexpr int NS   = 16;         // unit slices (32 units each)

typedef __attribute__((ext_vector_type(8))) short bf16x8;
typedef __attribute__((ext_vector_type(4))) float f32x4;

__device__ __forceinline__ unsigned short f2bf(float f){
  union { float f; unsigned u; } v; v.f = f;
  unsigned r = v.u + 0x7fffu + ((v.u >> 16) & 1u);
  return (unsigned short)(r >> 16);
}
__device__ __forceinline__ float fsig(float x){ return 1.f / (1.f + __expf(-x)); }
__device__ __forceinline__ float ftanh(float x){ return 1.f - 2.f / (__expf(2.f * x) + 1.f); }
__device__ __forceinline__ void vdrain(){ asm volatile("s_waitcnt vmcnt(0)" ::: "memory"); }

// device-scope (memory-side, placement-independent) flag ops — R12-proven
__device__ __forceinline__ int ld_flag_sc1(const int* p){
  int v;
  asm volatile("global_load_dword %0, %1, off sc0 sc1\n\ts_waitcnt vmcnt(0)"
               : "=v"(v) : "v"(p) : "memory");
  return v;
}
__device__ __forceinline__ void st_sc1_b32(void* p, int v){
  asm volatile("global_store_dword %0, %1, off sc0 sc1" :: "v"(p), "v"(v) : "memory");
}
__device__ __forceinline__ bf16x8 pack8(float4 a, float4 b){
  bf16x8 w;
  w[0]=(short)f2bf(a.x); w[1]=(short)f2bf(a.y); w[2]=(short)f2bf(a.z); w[3]=(short)f2bf(a.w);
  w[4]=(short)f2bf(b.x); w[5]=(short)f2bf(b.y); w[6]=(short)f2bf(b.z); w[7]=(short)f2bf(b.w);
  return w;
}

// Persistent pipelined 2-layer LSTM — placement-independent, 16-wide rendezvous,
// DEDUPLICATED h reads: each WG loads the 16-row h tile ONCE (cooperative sc1
// loads, 32 B/thread, distinct addresses) into a 16 KB XOR-swizzled LDS tile;
// all 8 waves read MFMA fragments from LDS. Cuts uncached read traffic 8x
// (48 MB/step -> 6 MB/step) — the suspected hidden bandwidth roofline.
// Everything else (roles, flags, protocol, liveness caps) = R16/R17.
__global__ __launch_bounds__(512, 1)
void lstm_persist(const float* __restrict__ text,
                  const float* __restrict__ Wih0, const float* __restrict__ Whh0,
                  const float* __restrict__ bih0, const float* __restrict__ bhh0,
                  const float* __restrict__ Wih1, const float* __restrict__ Whh1,
                  const float* __restrict__ bih1, const float* __restrict__ bhh1,
                  unsigned short* __restrict__ h0x,   // [256][128][512] write-once
                  unsigned short* __restrict__ h1r,   // [4][128][512] ring
                  float* __restrict__ H1f,            // [128][512] final h1 fp32
                  int* __restrict__ F)                // [2][8][256][16] flags
{
  extern __shared__ char lds[];     // 0..131071: W_ih (swizzled); 131072..147455: h tile
  char* Wlds  = lds;
  char* Htile = lds + 131072;
  __shared__ int s_abort;

  const int wg    = blockIdx.x;
  const int layer = wg >> 7;
  const int grp   = (wg >> 4) & 7;
  const int slice = wg & 15;
  const int m0    = grp * 16;
  const int u0    = slice * 32;
  const int tid   = threadIdx.x;
  const int wv    = tid >> 6;     // col-frag index 0..7
  const int l     = tid & 63;
  const int lj    = l & 15;
  const int lk    = l >> 4;

  if (tid == 0) s_abort = 0;

  int* F0g = F + ((0 * NG + grp) * TS) * NS;   // layer-0 flags, this grp
  int* F1g = F + ((1 * NG + grp) * TS) * NS;   // layer-1 flags, this grp

  const float* Wihl = layer ? Wih1 : Wih0;
  const float* Whhl = layer ? Whh1 : Whh0;

  // ---- one-time: W_ih slice -> LDS (f32 -> bf16, swizzled) ----
  for (int it = tid; it < 128 * 64; it += 512){
    int c = it >> 6, kg = it & 63;
    int unit = u0 + (c >> 2);
    int gate = c & 3;
    const float* s = Wihl + (size_t)(gate * HD + unit) * HD + kg * 8;
    *(bf16x8*)(Wlds + c * 1024 + ((kg ^ (c & 7)) << 4)) =
        pack8(((const float4*)s)[0], ((const float4*)s)[1]);
  }

  // ---- one-time: W_hh slice -> registers (64 VGPR/lane) ----
  const int j      = wv * 16 + lj;
  const int myunit = u0 + (j >> 2);
  const int mygate = j & 3;
  bf16x8 bPost[16];
  {
    const float* s0 = Whhl + (size_t)(mygate * HD + myunit) * HD + lk * 8;
    #pragma unroll
    for (int kk = 0; kk < 16; ++kk){
      const float* s = s0 + kk * 32;
      bPost[kk] = pack8(((const float4*)s)[0], ((const float4*)s)[1]);
    }
  }
  const float bgv = (layer ? bih1 : bih0)[mygate * HD + myunit]
                  + (layer ? bhh1 : bhh0)[mygate * HD + myunit];
  const int cboff = j * 1024;                   // W_ih col byte base in LDS
  const int swz   = lj & 7;

  float cst[4] = {0.f, 0.f, 0.f, 0.f};
  __syncthreads();   // LDS staged, s_abort visible

  auto ldsB = [&](int kg)->bf16x8 {
    return *(const bf16x8*)(Wlds + cboff + ((kg ^ swz) << 4));
  };
  // h-tile fragment read (row lj, k-chunk kc, k-group lk), XOR-swizzled
  auto ldsH = [&](int kc)->bf16x8 {
    int byte = kc * 64 + lk * 16;
    return *(const bf16x8*)(Htile + lj * 1024 + (byte ^ ((lj & 15) << 4)));
  };
  // cooperative tile stage: 512 thr x 32 B, distinct sc1 addrs -> LDS swizzled.
  // Caller brackets with __syncthreads().
  auto stage = [&](const unsigned short* src){
    const int r = tid >> 5, c = tid & 31;
    const char* gp = (const char*)(src + (size_t)(m0 + r) * HD) + c * 32;
    f32x4 t0, t1;
    asm volatile("global_load_dwordx4 %0, %2, off sc0 sc1\n\t"
                 "global_load_dwordx4 %1, %2, off offset:16 sc0 sc1\n\t"
                 "s_waitcnt vmcnt(0)"
                 : "=&v"(t0), "=&v"(t1) : "v"(gp) : "memory");
    char* rb = Htile + r * 1024;
    *(f32x4*)(rb + (((c * 32)      ^ ((r & 15) << 4)))) = t0;
    *(f32x4*)(rb + (((c * 32 + 16) ^ ((r & 15) << 4)))) = t1;
  };
  // wave-0 poll of 16 flags; hot spin then sleep backoff; 2M liveness cap.
  auto pollwait = [&](const int* base){
    if (*(volatile int*)&s_abort) return;
    const int* fp = base + (l & 15);
    int it = 0;
    for (;;){
      int v = ld_flag_sc1(fp);
      if (__all(v != 0)) break;
      ++it;
      if (it > 4096){
        if (it > 2000000){ s_abort = 1; break; }
        __builtin_amdgcn_s_sleep(1);
      }
    }
  };
  // cell update; packed sc1 h store (dword = 2 units); optional fp32 final write
  auto cellstore = [&](const f32x4& aP, const f32x4& aQ,
                       unsigned short* __restrict__ hslab, bool wrF){
    #pragma unroll
    for (int r = 0; r < 4; ++r){
      float v  = aP[r] + aQ[r] + bgv;
      float v1 = __shfl_xor(v, 1);
      float v2 = __shfl_xor(v, 2);
      float v3 = __shfl_xor(v, 3);
      auto pick = [&](int m)->float {
        return m == 0 ? v : (m == 1 ? v1 : (m == 2 ? v2 : v3));
      };
      float gi = pick(mygate);
      float gf = pick(mygate ^ 1);
      float gg = pick(mygate ^ 2);
      float go = pick(mygate ^ 3);
      float i_ = fsig(gi);
      float f_ = fsig(gf);
      float g_ = ftanh(gg);
      float o_ = fsig(go);
      float c  = f_ * cst[r] + i_ * g_;
      cst[r] = c;
      float h  = o_ * ftanh(c);
      int row  = m0 + lk * 4 + r;
      int hb   = (int)f2bf(h);
      int pb   = __shfl_xor(hb, 4);          // partner unit (myunit+1)
      if ((j & 7) == 0)                      // even-unit, gate 0 lanes
        st_sc1_b32((char*)hslab + ((size_t)row * HD + myunit) * 2,
                   (hb & 0xffff) | (pb << 16));
      if (wrF && mygate == 0)
        H1f[(size_t)row * HD + myunit] = h;
    }
  };
  // L0 input projection: text f32 direct (plain cached), cvt in-flight, W_ih LDS
  auto preX = [&](int t, f32x4& acc){
    int arow = m0 + lj;
    int b    = arow & 63;
    int ts2  = (arow < 64) ? t : (TS - 1 - t);
    const float* src = text + ((size_t)b * TS + ts2) * HD + lk * 8;
    acc = (f32x4){0.f, 0.f, 0.f, 0.f};
    #pragma unroll
    for (int kk = 0; kk < 16; ++kk){
      const float* s = src + kk * 32;
      bf16x8 a = pack8(((const float4*)s)[0], ((const float4*)s)[1]);
      acc = __builtin_amdgcn_mfma_f32_16x16x32_bf16(a, ldsB(kk * 4 + lk), acc, 0, 0, 0);
    }
  };

  if (layer == 0){
    // ================= layer 0: free-running (no backpressure ever) ==========
    f32x4 accPre;
    preX(0, accPre);
    for (int t = 0; t < TS; ++t){
      f32x4 accPost = {0.f, 0.f, 0.f, 0.f};
      if (t > 0){
        if (wv == 0) pollwait(F0g + (t - 1) * NS);
        __syncthreads();
        stage(h0x + (size_t)(t - 1) * SLAB);   // dedup: 16 KB once per WG
        __syncthreads();
        #pragma unroll
        for (int kk = 0; kk < 16; ++kk)
          accPost = __builtin_amdgcn_mfma_f32_16x16x32_bf16(
                      ldsH(kk), bPost[kk], accPost, 0, 0, 0);
      }
      cellstore(accPre, accPost, h0x + (size_t)t * SLAB, false);
      vdrain();                 // sc1 stores acked; also orders LDS consume
      __syncthreads();          // before next iteration's stage (WAR)
      if (tid == 0) st_sc1_b32(F0g + t * NS + slice, 1);
      if (t + 1 < TS) preX(t + 1, accPre);   // off critical path
    }
  } else {
    // ================= layer 1: chases L0 ====================================
    f32x4 accPre = {0.f, 0.f, 0.f, 0.f};
    {
      if (wv == 0) pollwait(F0g + 0);
      __syncthreads();
      stage(h0x);
      __syncthreads();
      #pragma unroll
      for (int kk = 0; kk < 16; ++kk)
        accPre = __builtin_amdgcn_mfma_f32_16x16x32_bf16(
                   ldsH(kk), ldsB(kk * 4 + lk), accPre, 0, 0, 0);
    }
    for (int t = 0; t < TS; ++t){
      f32x4 accPost = {0.f, 0.f, 0.f, 0.f};
      if (t > 0){
        if (wv == 0) pollwait(F1g + (t - 1) * NS);   // peers done t-1 (pacing)
        __syncthreads();
        stage(h1r + (size_t)((t - 1) & 3) * SLAB);
        __syncthreads();
        #pragma unroll
        for (int kk = 0; kk < 16; ++kk)
          accPost = __builtin_amdgcn_mfma_f32_16x16x32_bf16(
                      ldsH(kk), bPost[kk], accPost, 0, 0, 0);
      }
      cellstore(accPre, accPost, h1r + (size_t)(t & 3) * SLAB, t == TS - 1);
      vdrain();
      __syncthreads();
      if (tid == 0) st_sc1_b32(F1g + t * NS + slice, 1);
      if (t + 1 < TS){
        // prefetch h0x[t+1] AFTER release (off pacing chain; L0 runs ahead)
        if (wv == 0) pollwait(F0g + (t + 1) * NS);
        __syncthreads();
        stage(h0x + (size_t)(t + 1) * SLAB);
        __syncthreads();
        accPre = (f32x4){0.f, 0.f, 0.f, 0.f};
        #pragma unroll
        for (int kk = 0; kk < 16; ++kk)
          accPre = __builtin_amdgcn_mfma_f32_16x16x32_bf16(
                     ldsH(kk), ldsB(kk * 4 + lk), accPre, 0, 0, 0);
      }
    }
  }
}

// out[b] = dot(h1_fwd[b], Wlin[0:512]) + dot(h1_rev[b], Wlin[512:1024]) + blin
__global__ void final_linear(const float* __restrict__ H1f, const float* __restrict__ Wlin,
                             const float* __restrict__ blin, float* __restrict__ out){
  int b = blockIdx.x, l = threadIdx.x;
  float s = 0.f;
  for (int jj = l; jj < HD; jj += 64) s += H1f[(size_t)b * HD + jj]        * Wlin[jj];
  for (int jj = l; jj < HD; jj += 64) s += H1f[(size_t)(NB + b) * HD + jj] * Wlin[HD + jj];
  #pragma unroll
  for (int off = 32; off; off >>= 1) s += __shfl_down(s, off);
  if (l == 0) out[b] = s + blin[0];
}

extern "C" void kernel_launch(void* const* d_in, const int* in_sizes, int n_in,
                              void* d_out, int out_size, void* d_ws, size_t ws_size,
                              hipStream_t stream)
{
  const float* text = (const float*)d_in[0];
  const float* Wih0 = (const float*)d_in[1];
  const float* Whh0 = (const float*)d_in[2];
  const float* bih0 = (const float*)d_in[3];
  const float* bhh0 = (const float*)d_in[4];
  const float* Wih1 = (const float*)d_in[5];
  const float* Whh1 = (const float*)d_in[6];
  const float* bih1 = (const float*)d_in[7];
  const float* bhh1 = (const float*)d_in[8];
  const float* Wlin = (const float*)d_in[9];
  const float* blin = (const float*)d_in[10];

  // ---- ws layout (~33 MiB) ----
  uint8_t* p = (uint8_t*)d_ws;
  unsigned short* h0x = (unsigned short*)p; p += (size_t)TS * SLAB * 2;        // 32 MiB
  unsigned short* h1r = (unsigned short*)p; p += (size_t)4 * SLAB * 2;         // 512 KiB
  float* H1f          = (float*)p;          p += (size_t)SLAB * 4;             // 256 KiB
  int* F              = (int*)p;            p += (size_t)2 * NG * TS * NS * 4; // 256 KiB

  // deterministic init: flags zero at kernel start
  hipMemsetAsync(F, 0, (size_t)2 * NG * TS * NS * 4, stream);

  hipFuncSetAttribute((const void*)lstm_persist,
                      hipFuncAttributeMaxDynamicSharedMemorySize, 147456);

  const float* A0 = text;
  const float *A1 = Wih0, *A2 = Whh0, *A3 = bih0, *A4 = bhh0;
  const float *A5 = Wih1, *A6 = Whh1, *A7 = bih1, *A8 = bhh1;
  unsigned short* B0 = h0x; unsigned short* B1 = h1r;
  float* B2 = H1f; int* B3 = F;
  void* args[] = {(void*)&A0,
                  (void*)&A1, (void*)&A2, (void*)&A3, (void*)&A4,
                  (void*)&A5, (void*)&A6, (void*)&A7, (void*)&A8,
                  (void*)&B0, (void*)&B1, (void*)&B2, (void*)&B3};
  hipLaunchCooperativeKernel((void*)lstm_persist, dim3(256), dim3(512),
                             args, 147456, stream);

  final_linear<<<NB, 64, 0, stream>>>(H1f, Wlin, blin, (float*)d_out);
}